// Round 1
// baseline (452.469 us; speedup 1.0000x reference)
//
#include <hip/hip_runtime.h>

// ContinuousGameOfLife: x (16, 2048, 2048) f32 -> out same shape.
// around = 3x3 wrap-stencil sum minus center; smooth B3/S23 rule.
// Memory-bound: 512 MiB ideal traffic -> ~85 us floor at 6.3 TB/s.
//
// R1 changes vs 437.8us baseline:
//  - RPT 16 -> 32: vertical read amplification (RPT+2)/RPT 1.125 -> 1.0625.
//    Grid = 2x64x16 = 2048 blocks x 4 waves = 8192 waves = exact 32-wave/CU fill.
//  - Non-temporal output stores: output (256 MiB, never re-read) no longer
//    evicts the input working set (256 MiB == L3 size), so y-halo re-reads
//    stay L3 hits instead of going back to HBM.

#define GOL_H 2048
#define GOL_W 2048
#define GOL_B 16
#define RPT 32            // rows per thread: read amplification (RPT+2)/RPT = 1.0625
#define BLOCK 256         // threads per block; each thread owns 4 consecutive cols

typedef float f32x4 __attribute__((ext_vector_type(4)));

__device__ __forceinline__ float fast_sigmoid(float z) {
    // sigmoid(z) = 1 / (1 + exp(-z)); z range here is [-45, 35] -> no overflow
    float e = __builtin_amdgcn_exp2f(-z * 1.4426950408889634f);
    return __builtin_amdgcn_rcpf(1.0f + e);
}

__device__ __forceinline__ float game_rule(float cell, float a) {
    const float BETA = 10.0f;
    float s35 = fast_sigmoid(BETA * (3.5f - a));
    float s15 = fast_sigmoid(BETA * (a - 1.5f));
    float s25 = fast_sigmoid(BETA * (a - 2.5f));
    // cell*s15*s35 + (1-cell)*s25*s35 = s35 * (s25 + cell*(s15 - s25))
    return s35 * (s25 + cell * (s15 - s25));
}

// Load one input row segment: aligned float4 at c0 plus wrap-indexed scalar halos.
// Returns triple-sums t (horizontal 3-sums for the 4 columns) and raw center v.
__device__ __forceinline__ void load_row(const float* __restrict__ row, int c0,
                                         int cl, int cr, float4& t, float4& v) {
    v = *(const float4*)(row + c0);
    float l = row[cl];
    float r = row[cr];
    t.x = l   + v.x + v.y;
    t.y = v.x + v.y + v.z;
    t.z = v.y + v.z + v.w;
    t.w = v.z + v.w + r;
}

__global__ __launch_bounds__(BLOCK)
void gol_kernel(const float* __restrict__ x, float* __restrict__ out) {
    const int b  = blockIdx.z;
    const int c0 = (blockIdx.x * BLOCK + threadIdx.x) * 4;   // first of 4 columns
    const int r0 = blockIdx.y * RPT;
    const int cl = (c0 - 1) & (GOL_W - 1);
    const int cr = (c0 + 4) & (GOL_W - 1);

    const float* xp = x   + (size_t)b * GOL_H * GOL_W;
    float*       op = out + (size_t)b * GOL_H * GOL_W;

    float4 tp, tc, tn, vc, vn, vdummy;

    // prime rows r0-1 (wrap) and r0
    load_row(xp + (size_t)((r0 - 1) & (GOL_H - 1)) * GOL_W, c0, cl, cr, tp, vdummy);
    load_row(xp + (size_t)r0 * GOL_W,                       c0, cl, cr, tc, vc);

#pragma unroll 4
    for (int i = 0; i < RPT; ++i) {
        const int r = r0 + i;
        load_row(xp + (size_t)((r + 1) & (GOL_H - 1)) * GOL_W, c0, cl, cr, tn, vn);

        f32x4 o;
        o.x = game_rule(vc.x, tp.x + tc.x + tn.x - vc.x);
        o.y = game_rule(vc.y, tp.y + tc.y + tn.y - vc.y);
        o.z = game_rule(vc.z, tp.z + tc.z + tn.z - vc.z);
        o.w = game_rule(vc.w, tp.w + tc.w + tn.w - vc.w);

        // Non-temporal: output is write-once, keep it out of L2/L3 so the
        // input working set (== L3 capacity) stays resident for halo reuse.
        __builtin_nontemporal_store(o, (f32x4*)(op + (size_t)r * GOL_W + c0));

        tp = tc; tc = tn; vc = vn;
    }
}

extern "C" void kernel_launch(void* const* d_in, const int* in_sizes, int n_in,
                              void* d_out, int out_size, void* d_ws, size_t ws_size,
                              hipStream_t stream) {
    const float* x = (const float*)d_in[0];
    float* out = (float*)d_out;

    // grid: x over column strips (2048 / (4*256) = 2), y over row chunks, z over batch
    dim3 grid(GOL_W / (4 * BLOCK), GOL_H / RPT, GOL_B);
    dim3 block(BLOCK);
    gol_kernel<<<grid, block, 0, stream>>>(x, out);
}

// Round 2
// 435.643 us; speedup vs baseline: 1.0386x; 1.0386x over previous
//
#include <hip/hip_runtime.h>

// ContinuousGameOfLife: x (16, 2048, 2048) f32 -> out same shape.
// around = 3x3 wrap-stencil sum minus center; smooth B3/S23 rule.
// Memory-bound target: 544 MiB actual traffic -> ~90 us floor at 6.3 TB/s.
//
// R2 changes vs R1 (452.5us) / R0 baseline (437.9us):
//  - REVERT R1: RPT back to 16, plain stores (nt stores + RPT=32 cost +15us).
//  - game_rule collapsed from 3 exp + 3 rcp to 1 exp + 1 rcp:
//      u = e^{10a}:  s15=u/(u+e15), s25=u/(u+e25), s35=e35/(u+e35)
//      result = e35*u*(u + e15 + cell*(e25-e15)) / [(u+e15)(u+e25)(u+e35)]
//    Factors pre-scaled by 2^-40 to stay in fp32 range; exp arg clamped so
//    u <= 2^75 (true result there < 4e-8). Trans-pipe occupancy drops
//    ~82us -> ~27us, leaving HBM as the sole binding constraint.

#define GOL_H 2048
#define GOL_W 2048
#define GOL_B 16
#define RPT 16            // rows per thread: read amplification (RPT+2)/RPT = 1.125
#define BLOCK 256         // threads per block; each thread owns 4 consecutive cols

// Constants for the collapsed rule (all scaled by 2^-40):
//   C15 = e^15 * 2^-40, C25 = e^25 * 2^-40, C35 = e^35 * 2^-40
#define LOG2E10 14.426950408889634f   // 10/ln(2)
#define C15 2.9731544e-06f
#define C25 0.06548808f
#define C35 1442.4719f
#define C2515 0.06548511f             // C25 - C15

__device__ __forceinline__ float game_rule(float cell, float a) {
    float t = __builtin_fmaf(LOG2E10, a, -40.0f);   // log2(u * 2^-40)
    t = fminf(t, 35.0f);                            // clamp: u <= 2^75
    float w = __builtin_amdgcn_exp2f(t);            // u * 2^-40
    float p = w + C15;                              // (u+e15) * 2^-40
    float q = w + C25;                              // (u+e25) * 2^-40
    float r = w + C35;                              // (u+e35) * 2^-40
    float f = __builtin_fmaf(cell, C2515, p);       // (u + e15 + cell*(e25-e15)) * 2^-40
    float num = C35 * w * f;
    float den = p * q * r;
    return num * __builtin_amdgcn_rcpf(den);
}

// Load one input row segment: aligned float4 at c0 plus wrap-indexed scalar halos.
// Returns triple-sums t (horizontal 3-sums for the 4 columns) and raw center v.
__device__ __forceinline__ void load_row(const float* __restrict__ row, int c0,
                                         int cl, int cr, float4& t, float4& v) {
    v = *(const float4*)(row + c0);
    float l = row[cl];
    float r = row[cr];
    t.x = l   + v.x + v.y;
    t.y = v.x + v.y + v.z;
    t.z = v.y + v.z + v.w;
    t.w = v.z + v.w + r;
}

__global__ __launch_bounds__(BLOCK)
void gol_kernel(const float* __restrict__ x, float* __restrict__ out) {
    const int b  = blockIdx.z;
    const int c0 = (blockIdx.x * BLOCK + threadIdx.x) * 4;   // first of 4 columns
    const int r0 = blockIdx.y * RPT;
    const int cl = (c0 - 1) & (GOL_W - 1);
    const int cr = (c0 + 4) & (GOL_W - 1);

    const float* xp = x   + (size_t)b * GOL_H * GOL_W;
    float*       op = out + (size_t)b * GOL_H * GOL_W;

    float4 tp, tc, tn, vc, vn, vdummy;

    // prime rows r0-1 (wrap) and r0
    load_row(xp + (size_t)((r0 - 1) & (GOL_H - 1)) * GOL_W, c0, cl, cr, tp, vdummy);
    load_row(xp + (size_t)r0 * GOL_W,                       c0, cl, cr, tc, vc);

#pragma unroll 4
    for (int i = 0; i < RPT; ++i) {
        const int r = r0 + i;
        load_row(xp + (size_t)((r + 1) & (GOL_H - 1)) * GOL_W, c0, cl, cr, tn, vn);

        float4 o;
        o.x = game_rule(vc.x, tp.x + tc.x + tn.x - vc.x);
        o.y = game_rule(vc.y, tp.y + tc.y + tn.y - vc.y);
        o.z = game_rule(vc.z, tp.z + tc.z + tn.z - vc.z);
        o.w = game_rule(vc.w, tp.w + tc.w + tn.w - vc.w);

        *(float4*)(op + (size_t)r * GOL_W + c0) = o;

        tp = tc; tc = tn; vc = vn;
    }
}

extern "C" void kernel_launch(void* const* d_in, const int* in_sizes, int n_in,
                              void* d_out, int out_size, void* d_ws, size_t ws_size,
                              hipStream_t stream) {
    const float* x = (const float*)d_in[0];
    float* out = (float*)d_out;

    // grid: x over column strips (2048 / (4*256) = 2), y over row chunks, z over batch
    dim3 grid(GOL_W / (4 * BLOCK), GOL_H / RPT, GOL_B);
    dim3 block(BLOCK);
    gol_kernel<<<grid, block, 0, stream>>>(x, out);
}